// Round 3
// baseline (1274.522 us; speedup 1.0000x reference)
//
#include <hip/hip_runtime.h>
#include <hip/hip_bf16.h>
#include <math.h>

// Problem constants (fixed by the reference setup_inputs)
#define BB 32
#define PP 24564
#define OO 16
#define CC 81
#define BP (BB * PP)
#define CHUNK 1024   // priors per k_match_a block; ceil(PP/CHUNK)=24 chunks

typedef unsigned long long ull;

__device__ __forceinline__ float sl1(float x) {
    float ax = fabsf(x);
    return ax < 1.0f ? 0.5f * ax * ax : ax - 0.5f;
}

// ---------------------------------------------------------------------------
// K1a: matching, parallel over (chunk, batch). Writes per-prior packed code
//   code = tgt | (best_truth_idx << 8), tgt = (iou<0.5) ? 0 : label
// and per-truth best-prior via packed-key atomicMax:
//   key = (iou_bits << 32) | (0xFFFFFFFF - p)   -> max iou, tie: smallest p
// ---------------------------------------------------------------------------
__global__ __launch_bounds__(256) void k_match_a(
        const float* __restrict__ priors, const float* __restrict__ truths,
        const int* __restrict__ labels, int* __restrict__ codes,
        ull* __restrict__ best_prior /* [BB][OO], pre-zeroed */) {
    const int b = blockIdx.y;
    const int p0 = blockIdx.x * CHUNK;
    const int tid = threadIdx.x;
    __shared__ float tr[OO][4];
    __shared__ float tarea[OO];
    __shared__ int slab[OO];
    __shared__ ull red[OO];
    if (tid < OO * 4) ((float*)tr)[tid] = truths[b * OO * 4 + tid];
    if (tid < OO) { red[tid] = 0ull; slab[tid] = labels[b * OO + tid]; }
    __syncthreads();
    if (tid < OO) tarea[tid] = (tr[tid][2] - tr[tid][0]) * (tr[tid][3] - tr[tid][1]);
    __syncthreads();

    float bpv[OO];
    int bpi[OO];
#pragma unroll
    for (int o = 0; o < OO; o++) { bpv[o] = -1.0f; bpi[o] = -1; }

    const int pend = (p0 + CHUNK < PP) ? p0 + CHUNK : PP;
    for (int p = p0 + tid; p < pend; p += 256) {
        const float4 pr = ((const float4*)priors)[p];
        const float x1 = pr.x - pr.z * 0.5f, y1 = pr.y - pr.w * 0.5f;
        const float x2 = pr.x + pr.z * 0.5f, y2 = pr.y + pr.w * 0.5f;
        const float parea = (x2 - x1) * (y2 - y1);
        float best = -1.0f;
        int bidx = 0;
#pragma unroll
        for (int o = 0; o < OO; o++) {
            const float lx = fmaxf(tr[o][0], x1), ly = fmaxf(tr[o][1], y1);
            const float rx = fminf(tr[o][2], x2), ry = fminf(tr[o][3], y2);
            const float iw = fmaxf(rx - lx, 0.0f), ih = fmaxf(ry - ly, 0.0f);
            const float inter = iw * ih;
            const float iou = inter / (tarea[o] + parea - inter);
            if (iou > best) { best = iou; bidx = o; }          // first-max over o
            if (iou > bpv[o]) { bpv[o] = iou; bpi[o] = p; }    // p ascending per thread
        }
        const int tgt = (best < 0.5f) ? 0 : slab[bidx];
        codes[(size_t)b * PP + p] = tgt | (bidx << 8);
    }

#pragma unroll
    for (int o = 0; o < OO; o++) {
        if (bpi[o] >= 0) {
            const ull key = ((ull)__float_as_uint(bpv[o]) << 32) |
                            (ull)(0xFFFFFFFFu - (unsigned)bpi[o]);
            atomicMax(&red[o], key);
        }
    }
    __syncthreads();
    if (tid < OO && red[tid] != 0ull)
        atomicMax(&best_prior[b * OO + tid], red[tid]);
}

// K1b: sequential (numpy last-writer-wins) override, one thread per batch.
__global__ void k_match_b(const ull* __restrict__ best_prior,
                          const int* __restrict__ labels,
                          int* __restrict__ codes) {
    const int b = threadIdx.x;
    if (b >= BB) return;
    for (int o = 0; o < OO; o++) {
        const unsigned p = 0xFFFFFFFFu - (unsigned)(best_prior[b * OO + o] & 0xFFFFFFFFull);
        codes[(size_t)b * PP + p] = labels[b * OO + o] | (o << 8);  // iou=2.0 >= 0.5
    }
}

// ---------------------------------------------------------------------------
// K2: tile of 64 rows per block, staged through LDS with coalesced float4
// loads. LSE by 4 threads/row; epilogue by 64 threads, with codes/obj loads
// issued before the staging barrier (short dependency chains).
// acc: [0]=loss_l [1]=pos_ce_obj [2]=pos_ce_c [3]=neg_obj [4]=neg_c
// ---------------------------------------------------------------------------
__global__ __launch_bounds__(256) void k_ce(
        const float* __restrict__ conf, const float* __restrict__ obj,
        const float* __restrict__ loc, const float* __restrict__ priors,
        const float* __restrict__ truths, const int* __restrict__ codes,
        float* __restrict__ mining_obj, float* __restrict__ mining_c,
        int* __restrict__ num_pos, float* __restrict__ acc) {
    const int tid = threadIdx.x;
    const int row0 = blockIdx.x * 64;            // BP == 64 * gridDim.x exactly
    __shared__ float sconf[64 * CC];             // 20736 B
    __shared__ float slse[64];

    int code = 0;
    float2 o2 = make_float2(0.0f, 0.0f);
    if (tid < 64) {
        code = codes[row0 + tid];
        o2 = ((const float2*)obj)[row0 + tid];
    }

    const float4* src = (const float4*)(conf + (size_t)row0 * CC);
    float4* dst = (float4*)sconf;
    for (int i = tid; i < (64 * CC) / 4; i += 256) dst[i] = src[i];
    __syncthreads();

    const int r = tid >> 2;
    const int part = tid & 3;
    const float* rowp = sconf + r * CC;
    const int c0 = part * 20;
    const int c1 = (part == 3) ? CC : c0 + 20;   // 20,20,20,21
    float m = -INFINITY;
    for (int c = c0; c < c1; c++) m = fmaxf(m, rowp[c]);
    m = fmaxf(m, __shfl_xor(m, 1));
    m = fmaxf(m, __shfl_xor(m, 2));
    float s = 0.0f;
    for (int c = c0; c < c1; c++) s += __expf(rowp[c] - m);
    s += __shfl_xor(s, 1);
    s += __shfl_xor(s, 2);
    if (part == 0) slse[r] = m + __logf(s);
    __syncthreads();

    if (tid < 64) {
        const int row = row0 + tid;
        const int b = row / PP;
        const int tgt = code & 255;
        const int ti = code >> 8;
        const float ce_c = slse[tid] - sconf[tid * CC + tgt];

        const float mo = fmaxf(o2.x, o2.y);
        const float lse_o = mo + __logf(__expf(o2.x - mo) + __expf(o2.y - mo));
        const bool pos = tgt > 0;
        const float ce_o = lse_o - (pos ? o2.y : o2.x);

        mining_c[row]   = pos ? 0.0f : ce_c;
        mining_obj[row] = pos ? 0.0f : ce_o;

        if (pos) {
            const int p = row - b * PP;
            atomicAdd(&num_pos[b], 1);
            atomicAdd(&acc[1], ce_o);
            atomicAdd(&acc[2], ce_c);
            const float4 pr = ((const float4*)priors)[p];
            const float4 t  = ((const float4*)truths)[b * OO + ti];
            const float gcx = ((t.x + t.z) * 0.5f - pr.x) / (0.1f * pr.z);
            const float gcy = ((t.y + t.w) * 0.5f - pr.y) / (0.1f * pr.w);
            const float gw = logf((t.z - t.x) / pr.z) / 0.2f;
            const float gh = logf((t.w - t.y) / pr.w) / 0.2f;
            const float4 ld = ((const float4*)loc)[row];
            const float l = sl1(ld.x - gcx) + sl1(ld.y - gcy) +
                            sl1(ld.z - gw) + sl1(ld.w - gh);
            atomicAdd(&acc[0], l);
        }
    }
}

// ---------------------------------------------------------------------------
// K3: top-k sum via 4-pass byte radix-select. 64 blocks: {obj,c} x 32 batches.
// Wave-aggregated histogram atomics (CE values concentrate in 1-2 top-byte
// buckets -> raw same-address LDS atomics serialize 64-way; aggregation does
// one atomic per distinct bucket per wave). Bucket scan is wave-parallel.
// ---------------------------------------------------------------------------
__global__ __launch_bounds__(256) void k_select(
        const float* __restrict__ mining /* [2][B][P] */,
        const int* __restrict__ num_pos, float* __restrict__ acc,
        int* __restrict__ n1_acc) {
    const int arr = blockIdx.x >> 5;  // 0 = obj, 1 = c
    const int b = blockIdx.x & 31;
    const int tid = threadIdx.x;
    const float* x = mining + ((size_t)arr * BB + b) * PP;
    const int np = num_pos[b];
    long long k64 = 3LL * np;
    const int k = (int)(k64 < (long long)(PP - 1) ? k64 : (long long)(PP - 1));
    if (tid == 0 && arr == 0) atomicAdd(n1_acc, k);
    if (k <= 0) return;

    __shared__ unsigned hist[256];
    __shared__ unsigned s_prefix;
    __shared__ int s_krem;
    if (tid == 0) { s_prefix = 0u; s_krem = k; }
    __syncthreads();

    for (int shift = 24; shift >= 0; shift -= 8) {
        hist[tid] = 0u;
        __syncthreads();
        const unsigned prefix = s_prefix;
        const unsigned pmask = (shift == 24) ? 0u : (0xFFFFFFFFu << (shift + 8));

        for (int i = tid; i < PP; i += 256) {
            const unsigned u = __float_as_uint(x[i]);
            const bool pred = ((u & pmask) == prefix);
            const unsigned bucket = (u >> shift) & 255u;
            ull active = __ballot(pred);
            while (active) {
                const int leader = __ffsll((long long)active) - 1;
                const unsigned lb = __shfl(bucket, leader);
                const ull same = __ballot(pred && (bucket == lb));
                if ((tid & 63) == leader)
                    atomicAdd(&hist[lb], (unsigned)__popcll(same));
                active &= ~same;
            }
        }
        __syncthreads();

        // wave 0: parallel suffix scan over 256 buckets (descending), find
        // bucket where cumulative-from-top crosses krem.
        if (tid < 64) {
            const int krem = s_krem;
            const int b0 = 255 - 4 * tid;
            const unsigned c0 = hist[b0], c1 = hist[b0 - 1];
            const unsigned c2 = hist[b0 - 2], c3 = hist[b0 - 3];
            const unsigned lsum = c0 + c1 + c2 + c3;
            unsigned pre = lsum;
#pragma unroll
            for (int off = 1; off < 64; off <<= 1) {
                const unsigned t = __shfl_up(pre, off);
                if (tid >= off) pre += t;
            }
            const unsigned excl = pre - lsum;
            if (excl < (unsigned)krem && (unsigned)krem <= pre) {
                unsigned cum = excl;
                int sel = b0;
                if ((unsigned)krem <= cum + c0) { /* sel = b0 */ }
                else if ((unsigned)krem <= cum + c0 + c1) { sel = b0 - 1; cum += c0; }
                else if ((unsigned)krem <= cum + c0 + c1 + c2) { sel = b0 - 2; cum += c0 + c1; }
                else { sel = b0 - 3; cum += c0 + c1 + c2; }
                s_krem = krem - (int)cum;
                s_prefix = prefix | ((unsigned)sel << shift);
            }
        }
        __syncthreads();
    }

    const unsigned t = s_prefix;
    float lsum = 0.0f;
    unsigned lcnt = 0;
    for (int i = tid; i < PP; i += 256) {
        const float v = x[i];
        if (__float_as_uint(v) > t) { lsum += v; lcnt++; }
    }
    __shared__ float sred[256];
    __shared__ unsigned cred[256];
    sred[tid] = lsum;
    cred[tid] = lcnt;
    __syncthreads();
    for (int st = 128; st; st >>= 1) {
        if (tid < st) {
            sred[tid] += sred[tid + st];
            cred[tid] += cred[tid + st];
        }
        __syncthreads();
    }
    if (tid == 0) {
        const float tsum = sred[0] + (float)(k - (int)cred[0]) * __uint_as_float(t);
        atomicAdd(&acc[3 + arr], tsum);
    }
}

// K4: final scalars.
__global__ void k_final(const float* __restrict__ acc,
                        const int* __restrict__ num_pos,
                        const int* __restrict__ n1_acc,
                        float* __restrict__ out) {
    if (threadIdx.x == 0 && blockIdx.x == 0) {
        int N = 0;
        for (int b = 0; b < BB; b++) N += num_pos[b];
        const float fN = (float)(N > 1 ? N : 1);
        const int n1 = *n1_acc;
        const float fN1 = (float)(n1 > 1 ? n1 : 1);
        out[0] = acc[0] / fN;
        out[1] = (acc[2] + acc[4]) / fN;
        out[2] = 0.4f * (acc[1] + acc[3]) / fN1;
    }
}

extern "C" void kernel_launch(void* const* d_in, const int* in_sizes, int n_in,
                              void* d_out, int out_size, void* d_ws, size_t ws_size,
                              hipStream_t stream) {
    const float* loc_data  = (const float*)d_in[0];
    const float* conf_data = (const float*)d_in[1];
    const float* obj_data  = (const float*)d_in[2];
    const float* priors    = (const float*)d_in[3];
    const float* truths    = (const float*)d_in[4];
    const int*   labels    = (const int*)d_in[5];
    float* out = (float*)d_out;

    // Workspace layout (4-byte units):
    // [0, BP)            codes (int)
    // [BP, 3BP)          mining: [0]=obj, [1]=c
    // [3BP, 3BP+1024)    best_prior: 512 ull (zeroed)
    // [3BP+1024, ...)    num_pos (32 int), acc (8 f), n1 (int)  (zeroed)
    float* ws_f = (float*)d_ws;
    int*   codes = (int*)ws_f;
    float* mining = ws_f + (size_t)BP;
    ull*   best_prior = (ull*)(ws_f + 3 * (size_t)BP);
    int*   num_pos = (int*)(ws_f + 3 * (size_t)BP + 1024);
    float* acc = ws_f + 3 * (size_t)BP + 1024 + 32;
    int*   n1_acc = (int*)(ws_f + 3 * (size_t)BP + 1024 + 48);

    // zero best_prior + num_pos + acc + n1 in one shot
    hipMemsetAsync((void*)best_prior, 0, 8192, stream);

    dim3 mg((PP + CHUNK - 1) / CHUNK, BB);
    k_match_a<<<mg, 256, 0, stream>>>(priors, truths, labels, codes, best_prior);
    k_match_b<<<1, 32, 0, stream>>>(best_prior, labels, codes);

    k_ce<<<BP / 64, 256, 0, stream>>>(conf_data, obj_data, loc_data, priors,
                                      truths, codes,
                                      mining /*obj*/, mining + BP /*c*/,
                                      num_pos, acc);

    k_select<<<64, 256, 0, stream>>>(mining, num_pos, acc, n1_acc);

    k_final<<<1, 64, 0, stream>>>(acc, num_pos, n1_acc, out);
}

// Round 4
// 908.531 us; speedup vs baseline: 1.4028x; 1.4028x over previous
//
#include <hip/hip_runtime.h>
#include <hip/hip_bf16.h>
#include <math.h>

// Problem constants (fixed by the reference setup_inputs)
#define BB 32
#define PP 24564
#define OO 16
#define CC 81
#define BP (BB * PP)
#define CHUNK 1024   // priors per k_match_a block

typedef unsigned long long ull;

__device__ __forceinline__ float sl1(float x) {
    float ax = fabsf(x);
    return ax < 1.0f ? 0.5f * ax * ax : ax - 0.5f;
}

// ---------------------------------------------------------------------------
// K1a: matching. Writes per-prior packed code = tgt | (best_truth_idx << 8)
// and per-truth best-prior via packed-key atomicMax (max iou, tie: smallest p)
// ---------------------------------------------------------------------------
__global__ __launch_bounds__(256) void k_match_a(
        const float* __restrict__ priors, const float* __restrict__ truths,
        const int* __restrict__ labels, int* __restrict__ codes,
        ull* __restrict__ best_prior /* [BB][OO], pre-zeroed */) {
    const int b = blockIdx.y;
    const int p0 = blockIdx.x * CHUNK;
    const int tid = threadIdx.x;
    __shared__ float tr[OO][4];
    __shared__ float tarea[OO];
    __shared__ int slab[OO];
    __shared__ ull red[OO];
    if (tid < OO * 4) ((float*)tr)[tid] = truths[b * OO * 4 + tid];
    if (tid < OO) { red[tid] = 0ull; slab[tid] = labels[b * OO + tid]; }
    __syncthreads();
    if (tid < OO) tarea[tid] = (tr[tid][2] - tr[tid][0]) * (tr[tid][3] - tr[tid][1]);
    __syncthreads();

    float bpv[OO];
    int bpi[OO];
#pragma unroll
    for (int o = 0; o < OO; o++) { bpv[o] = -1.0f; bpi[o] = -1; }

    const int pend = (p0 + CHUNK < PP) ? p0 + CHUNK : PP;
    for (int p = p0 + tid; p < pend; p += 256) {
        const float4 pr = ((const float4*)priors)[p];
        const float x1 = pr.x - pr.z * 0.5f, y1 = pr.y - pr.w * 0.5f;
        const float x2 = pr.x + pr.z * 0.5f, y2 = pr.y + pr.w * 0.5f;
        const float parea = (x2 - x1) * (y2 - y1);
        float best = -1.0f;
        int bidx = 0;
#pragma unroll
        for (int o = 0; o < OO; o++) {
            const float lx = fmaxf(tr[o][0], x1), ly = fmaxf(tr[o][1], y1);
            const float rx = fminf(tr[o][2], x2), ry = fminf(tr[o][3], y2);
            const float iw = fmaxf(rx - lx, 0.0f), ih = fmaxf(ry - ly, 0.0f);
            const float inter = iw * ih;
            const float iou = inter / (tarea[o] + parea - inter);
            if (iou > best) { best = iou; bidx = o; }          // first-max over o
            if (iou > bpv[o]) { bpv[o] = iou; bpi[o] = p; }    // p ascending per thread
        }
        const int tgt = (best < 0.5f) ? 0 : slab[bidx];
        codes[(size_t)b * PP + p] = tgt | (bidx << 8);
    }

#pragma unroll
    for (int o = 0; o < OO; o++) {
        if (bpi[o] >= 0) {
            const ull key = ((ull)__float_as_uint(bpv[o]) << 32) |
                            (ull)(0xFFFFFFFFu - (unsigned)bpi[o]);
            atomicMax(&red[o], key);
        }
    }
    __syncthreads();
    if (tid < OO && red[tid] != 0ull)
        atomicMax(&best_prior[b * OO + tid], red[tid]);
}

// K1b: sequential (numpy last-writer-wins) override, one thread per batch.
__global__ void k_match_b(const ull* __restrict__ best_prior,
                          const int* __restrict__ labels,
                          int* __restrict__ codes) {
    const int b = threadIdx.x;
    if (b >= BB) return;
    for (int o = 0; o < OO; o++) {
        const unsigned p = 0xFFFFFFFFu - (unsigned)(best_prior[b * OO + o] & 0xFFFFFFFFull);
        codes[(size_t)b * PP + p] = labels[b * OO + o] | (o << 8);  // iou=2.0 >= 0.5
    }
}

// ---------------------------------------------------------------------------
// K2: wave-synchronous CE. Each wave owns a private 16-row LDS region:
// stages 324 float4 coalesced, computes LSE with 4 lanes/row from registers,
// epilogue on lanes 0..15. NO __syncthreads -- only intra-wave fences, so
// 28 resident waves/CU free-run and hide HBM latency off each other.
// acc: [0]=loss_l [1]=pos_ce_obj [2]=pos_ce_c [3]=neg_obj [4]=neg_c
// ---------------------------------------------------------------------------
__global__ __launch_bounds__(256) void k_ce(
        const float* __restrict__ conf, const float* __restrict__ obj,
        const float* __restrict__ loc, const float* __restrict__ priors,
        const float* __restrict__ truths, const int* __restrict__ codes,
        float* __restrict__ mining_obj, float* __restrict__ mining_c,
        int* __restrict__ num_pos, float* __restrict__ acc) {
    const int w = threadIdx.x >> 6;
    const int L = threadIdx.x & 63;
    const int rowbase = blockIdx.x * 64 + w * 16;   // BP == 64 * gridDim.x
    __shared__ float sconf[4][16 * CC];             // 5184 B per wave region
    __shared__ float slse[4][16];

    int code = 0;
    float2 o2 = make_float2(0.0f, 0.0f);
    if (L < 16) {
        code = codes[rowbase + L];
        o2 = ((const float2*)obj)[rowbase + L];
    }

    // stage 16 rows = 1296 floats = 324 float4 (16B-aligned: rowbase%16==0)
    const float4* src4 = (const float4*)conf + (size_t)rowbase * CC / 4;
    float4* dst4 = (float4*)sconf[w];
#pragma unroll
    for (int it = 0; it < 5; ++it) dst4[L + 64 * it] = src4[L + 64 * it];
    if (L < 4) dst4[320 + L] = src4[320 + L];

    __builtin_amdgcn_fence(__ATOMIC_ACQ_REL, "workgroup");
    __builtin_amdgcn_wave_barrier();

    const int r = L >> 2, part = L & 3;
    const float* rowp = sconf[w] + r * CC + part * 20;
    float rv[21];
#pragma unroll
    for (int c = 0; c < 20; ++c) rv[c] = rowp[c];
    rv[20] = (part == 3) ? rowp[20] : -INFINITY;    // 20,20,20,21 split of 81
    float m = rv[0];
#pragma unroll
    for (int c = 1; c < 21; ++c) m = fmaxf(m, rv[c]);
    m = fmaxf(m, __shfl_xor(m, 1));
    m = fmaxf(m, __shfl_xor(m, 2));
    float s = 0.0f;
#pragma unroll
    for (int c = 0; c < 21; ++c) s += __expf(rv[c] - m);  // exp(-inf)=0 pad
    s += __shfl_xor(s, 1);
    s += __shfl_xor(s, 2);
    if (part == 0) slse[w][r] = m + __logf(s);

    __builtin_amdgcn_fence(__ATOMIC_ACQ_REL, "workgroup");
    __builtin_amdgcn_wave_barrier();

    if (L < 16) {
        const int row = rowbase + L;
        const int b = row / PP;
        const int tgt = code & 255;
        const int ti = code >> 8;
        const float ce_c = slse[w][L] - sconf[w][L * CC + tgt];

        const float mo = fmaxf(o2.x, o2.y);
        const float lse_o = mo + __logf(__expf(o2.x - mo) + __expf(o2.y - mo));
        const bool pos = tgt > 0;
        const float ce_o = lse_o - (pos ? o2.y : o2.x);

        mining_c[row]   = pos ? 0.0f : ce_c;
        mining_obj[row] = pos ? 0.0f : ce_o;

        if (pos) {
            const int p = row - b * PP;
            atomicAdd(&num_pos[b], 1);
            atomicAdd(&acc[1], ce_o);
            atomicAdd(&acc[2], ce_c);
            const float4 pr = ((const float4*)priors)[p];
            const float4 t  = ((const float4*)truths)[b * OO + ti];
            const float gcx = ((t.x + t.z) * 0.5f - pr.x) / (0.1f * pr.z);
            const float gcy = ((t.y + t.w) * 0.5f - pr.y) / (0.1f * pr.w);
            const float gw = logf((t.z - t.x) / pr.z) / 0.2f;
            const float gh = logf((t.w - t.y) / pr.w) / 0.2f;
            const float4 ld = ((const float4*)loc)[row];
            const float l = sl1(ld.x - gcx) + sl1(ld.y - gcy) +
                            sl1(ld.z - gw) + sl1(ld.w - gh);
            atomicAdd(&acc[0], l);
        }
    }
}

// ---------------------------------------------------------------------------
// K3: top-k sum, register-resident 3-pass radix select (11/11/10 bits).
// 64 blocks (= {obj,c} x 32 batches) x 1024 threads; each thread holds 24
// values in registers (24*1024 = 24576 >= PP; pad 0.0 is neutral: it never
// exceeds T>=0 and contributes (k-cnt)*0 if T==0). One global read total.
// ---------------------------------------------------------------------------
__global__ __launch_bounds__(1024) void k_select(
        const float* __restrict__ mining /* [2][B][P] */,
        const int* __restrict__ num_pos, float* __restrict__ acc,
        int* __restrict__ n1_acc) {
    const int arr = blockIdx.x >> 5;  // 0 = obj, 1 = c
    const int b = blockIdx.x & 31;
    const int tid = threadIdx.x;
    const int lane = tid & 63, wid = tid >> 6;
    const float* x = mining + ((size_t)arr * BB + b) * PP;
    const int np = num_pos[b];
    const long long k64 = 3LL * np;
    const int k = (int)(k64 < (long long)(PP - 1) ? k64 : (long long)(PP - 1));
    if (tid == 0 && arr == 0) atomicAdd(n1_acc, k);
    if (k <= 0) return;  // uniform across block

    unsigned v[24];
#pragma unroll
    for (int j = 0; j < 24; ++j) {
        const int i = tid + j * 1024;
        v[j] = (i < PP) ? __float_as_uint(x[i]) : 0u;
    }

    __shared__ unsigned hist[2048];
    __shared__ unsigned wsum[16];
    __shared__ float fred[16];
    __shared__ unsigned ured[16];
    __shared__ unsigned s_prefix;
    __shared__ int s_krem;
    if (tid == 0) { s_prefix = 0u; s_krem = k; }

    const int shifts[3] = {21, 10, 0};
    const int nbits[3] = {11, 11, 10};
#pragma unroll
    for (int pass = 0; pass < 3; ++pass) {
        const int shift = shifts[pass];
        const int nb = 1 << nbits[pass];
        const unsigned bmask = (unsigned)(nb - 1);
        hist[tid] = 0u;
        if (nb > 1024) hist[tid + 1024] = 0u;
        __syncthreads();
        const unsigned prefix = s_prefix;
        const unsigned pmask = (pass == 0) ? 0u
                             : (0xFFFFFFFFu << (shift + nbits[pass]));
#pragma unroll
        for (int j = 0; j < 24; ++j) {
            const unsigned u = v[j];
            if ((u & pmask) == prefix)
                atomicAdd(&hist[(u >> shift) & bmask], 1u);
        }
        __syncthreads();

        // descending-bucket block inclusive scan; thread t owns top pair
        unsigned c0, local;
        int hi;
        if (nb == 2048) {
            hi = 2047 - 2 * tid;
            c0 = hist[hi];
            local = c0 + hist[hi - 1];
        } else {
            hi = 1023 - tid;
            c0 = hist[hi];
            local = c0;
        }
        unsigned incl = local;
#pragma unroll
        for (int off = 1; off < 64; off <<= 1) {
            const unsigned t = __shfl_up(incl, off);
            if (lane >= off) incl += t;
        }
        if (lane == 63) wsum[wid] = incl;
        __syncthreads();
        if (wid == 0) {
            unsigned wv = (lane < 16) ? wsum[lane] : 0u;
#pragma unroll
            for (int off = 1; off < 16; off <<= 1) {
                const unsigned t = __shfl_up(wv, off);
                if (lane >= off) wv += t;
            }
            if (lane < 16) wsum[lane] = wv;
        }
        __syncthreads();
        incl += (wid ? wsum[wid - 1] : 0u);
        const unsigned excl = incl - local;
        const int krem = s_krem;
        __syncthreads();  // all reads of s_krem done before the write below
        if (excl < (unsigned)krem && (unsigned)krem <= incl) {
            int sel = hi;
            unsigned cum = excl;
            if ((unsigned)krem > excl + c0) { sel = hi - 1; cum = excl + c0; }
            s_prefix = prefix | ((unsigned)sel << shift);
            s_krem = krem - (int)cum;
        }
        __syncthreads();
    }

    const unsigned T = s_prefix;  // exact bits of the k-th largest value
    float sum = 0.0f;
    unsigned cnt = 0;
#pragma unroll
    for (int j = 0; j < 24; ++j) {
        const unsigned u = v[j];
        if (u > T) { sum += __uint_as_float(u); cnt++; }
    }
#pragma unroll
    for (int off = 32; off; off >>= 1) {
        sum += __shfl_xor(sum, off);
        cnt += __shfl_xor(cnt, off);
    }
    if (lane == 0) { fred[wid] = sum; ured[wid] = cnt; }
    __syncthreads();
    if (tid == 0) {
        float ts = 0.0f;
        unsigned tc = 0;
        for (int i = 0; i < 16; i++) { ts += fred[i]; tc += ured[i]; }
        const float tsum = ts + (float)(k - (int)tc) * __uint_as_float(T);
        atomicAdd(&acc[3 + arr], tsum);
    }
}

// K4: final scalars.
__global__ void k_final(const float* __restrict__ acc,
                        const int* __restrict__ num_pos,
                        const int* __restrict__ n1_acc,
                        float* __restrict__ out) {
    if (threadIdx.x == 0 && blockIdx.x == 0) {
        int N = 0;
        for (int b = 0; b < BB; b++) N += num_pos[b];
        const float fN = (float)(N > 1 ? N : 1);
        const int n1 = *n1_acc;
        const float fN1 = (float)(n1 > 1 ? n1 : 1);
        out[0] = acc[0] / fN;
        out[1] = (acc[2] + acc[4]) / fN;
        out[2] = 0.4f * (acc[1] + acc[3]) / fN1;
    }
}

extern "C" void kernel_launch(void* const* d_in, const int* in_sizes, int n_in,
                              void* d_out, int out_size, void* d_ws, size_t ws_size,
                              hipStream_t stream) {
    const float* loc_data  = (const float*)d_in[0];
    const float* conf_data = (const float*)d_in[1];
    const float* obj_data  = (const float*)d_in[2];
    const float* priors    = (const float*)d_in[3];
    const float* truths    = (const float*)d_in[4];
    const int*   labels    = (const int*)d_in[5];
    float* out = (float*)d_out;

    // Workspace layout (4-byte units):
    // [0, BP)            codes (int)
    // [BP, 3BP)          mining: [0]=obj, [1]=c
    // [3BP, 3BP+1024)    best_prior: 512 ull (zeroed)
    // [3BP+1024, ...)    num_pos (32 int), acc (8 f), n1 (int)  (zeroed)
    float* ws_f = (float*)d_ws;
    int*   codes = (int*)ws_f;
    float* mining = ws_f + (size_t)BP;
    ull*   best_prior = (ull*)(ws_f + 3 * (size_t)BP);
    int*   num_pos = (int*)(ws_f + 3 * (size_t)BP + 1024);
    float* acc = ws_f + 3 * (size_t)BP + 1024 + 32;
    int*   n1_acc = (int*)(ws_f + 3 * (size_t)BP + 1024 + 48);

    hipMemsetAsync((void*)best_prior, 0, 8192, stream);

    dim3 mg((PP + CHUNK - 1) / CHUNK, BB);
    k_match_a<<<mg, 256, 0, stream>>>(priors, truths, labels, codes, best_prior);
    k_match_b<<<1, 32, 0, stream>>>(best_prior, labels, codes);

    k_ce<<<BP / 64, 256, 0, stream>>>(conf_data, obj_data, loc_data, priors,
                                      truths, codes,
                                      mining /*obj*/, mining + BP /*c*/,
                                      num_pos, acc);

    k_select<<<64, 1024, 0, stream>>>(mining, num_pos, acc, n1_acc);

    k_final<<<1, 64, 0, stream>>>(acc, num_pos, n1_acc, out);
}